// Round 1
// 1744.554 us; speedup vs baseline: 1.2703x; 1.2703x over previous
//
#include <hip/hip_runtime.h>
#include <stdint.h>

// Problem constants
#define BS_TOKENS 16384   // B*S
#define DIM 1024          // D
#define FF 4096           // F
#define NE 8              // experts
#define NSLOT_CAP 33792   // 264 * 128 (32768 slots + per-expert 128-alignment padding)
#define MT_TILES 264
#define CHUNK_TILES 33    // slot tiles per chunk; 8 chunks; H chunk = 34.6 MB

typedef float f32x4 __attribute__((ext_vector_type(4)));
typedef __bf16 bf16x8 __attribute__((ext_vector_type(8)));

__device__ __forceinline__ unsigned short f2bf(float f) {
  union { float f; unsigned u; } v; v.f = f;
  unsigned u = v.u;
  unsigned r = (u + 0x7FFFu + ((u >> 16) & 1u)) >> 16;  // RNE
  return (unsigned short)r;
}

// async 16B/lane global->LDS; LDS dest is wave-uniform base + lane*16
__device__ __forceinline__ void gload16(const void* g, void* s) {
  __builtin_amdgcn_global_load_lds(
      (const __attribute__((address_space(1))) unsigned int*)g,
      (__attribute__((address_space(3))) unsigned int*)s, 16, 0, 0);
}

// ---------------- pre-passes (fp32 inputs -> bf16 staging) ----------------

__global__ __launch_bounds__(256) void cvt_x_kernel(const float* __restrict__ x,
                                                    unsigned short* __restrict__ xb) {
  int i = blockIdx.x * 256 + threadIdx.x;
  float4 v = ((const float4*)x)[i];
  ushort4 o;
  o.x = f2bf(v.x); o.y = f2bf(v.y); o.z = f2bf(v.z); o.w = f2bf(v.w);
  ((ushort4*)xb)[i] = o;
}

// src fp32 [R][C] (per expert), dst bf16 [C][R]
__global__ __launch_bounds__(256) void transpose_cvt_kernel(
    const float* __restrict__ src, unsigned short* __restrict__ dst, int R, int C) {
  __shared__ unsigned short tile[32][33];
  size_t ebase = (size_t)blockIdx.z * R * C;
  int c0 = blockIdx.x * 32, r0 = blockIdx.y * 32;
  int tx = threadIdx.x & 31, ty = threadIdx.x >> 5;  // ty 0..7
#pragma unroll
  for (int i = 0; i < 32; i += 8)
    tile[ty + i][tx] = f2bf(src[ebase + (size_t)(r0 + ty + i) * C + c0 + tx]);
  __syncthreads();
#pragma unroll
  for (int i = 0; i < 32; i += 8)
    dst[ebase + (size_t)(c0 + ty + i) * R + r0 + tx] = tile[tx][ty + i];
}

// Wg fp32 [D][E] -> wgt fp32 [E][D] (tiny: 8192 elems)
__global__ __launch_bounds__(256) void cvt_wg_kernel(const float* __restrict__ Wg,
                                                     float* __restrict__ wgt) {
  int i = blockIdx.x * 256 + threadIdx.x;  // i over D*E
  int d = i >> 3, e = i & 7;
  wgt[e * DIM + d] = Wg[i];
}

// ---------------- router (fp32) ----------------
// 32 tokens/block (8/wave), coalesced float4 x reads, wgt [E][D] reads,
// per-block LDS histogram -> 8 global atomics per block (contention fix).

__global__ __launch_bounds__(256) void router_kernel(
    const float* __restrict__ x, const float* __restrict__ wgt,
    int* __restrict__ topidx, float* __restrict__ tgate, int* __restrict__ cnt) {
  __shared__ int scnt[NE];
  const int tid = threadIdx.x;
  if (tid < NE) scnt[tid] = 0;
  __syncthreads();
  const int wid = tid >> 6, l = tid & 63;
  const int tbase = blockIdx.x * 32 + wid * 8;
  for (int tt = 0; tt < 8; tt++) {
    int token = tbase + tt;
    const float4* xr4 = (const float4*)(x + (size_t)token * DIM);
    float acc[NE];
#pragma unroll
    for (int e = 0; e < NE; e++) acc[e] = 0.f;
#pragma unroll
    for (int k = 0; k < DIM / 256; k++) {  // 4 iters, 16B/lane
      float4 xv = xr4[l + 64 * k];
      int d = (l + 64 * k) * 4;
#pragma unroll
      for (int e = 0; e < NE; e++) {
        float4 wv = *(const float4*)(wgt + e * DIM + d);
        acc[e] += xv.x * wv.x + xv.y * wv.y + xv.z * wv.z + xv.w * wv.w;
      }
    }
#pragma unroll
    for (int e = 0; e < NE; e++) {
#pragma unroll
      for (int off = 32; off > 0; off >>= 1) acc[e] += __shfl_xor(acc[e], off);
    }
    if (l == 0) {
      float m = acc[0];
#pragma unroll
      for (int e = 1; e < NE; e++) m = fmaxf(m, acc[e]);
      float p[NE];
#pragma unroll
      for (int e = 0; e < NE; e++) p[e] = __expf(acc[e] - m);
      int i1 = 0;
#pragma unroll
      for (int e = 1; e < NE; e++) if (p[e] > p[i1]) i1 = e;   // strict > : first index on tie
      int i2 = -1;
#pragma unroll
      for (int e = 0; e < NE; e++) {
        if (e == i1) continue;
        if (i2 < 0 || p[e] > p[i2]) i2 = e;
      }
      float s = p[i1] + p[i2];
      topidx[2 * token] = i1; topidx[2 * token + 1] = i2;
      tgate[2 * token] = p[i1] / s; tgate[2 * token + 1] = p[i2] / s;
      atomicAdd(&scnt[i1], 1); atomicAdd(&scnt[i2], 1);
    }
  }
  __syncthreads();
  if (tid < NE) atomicAdd(&cnt[tid], scnt[tid]);
}

__global__ void mk_offs_kernel(const int* __restrict__ cnt, int* __restrict__ offs) {
  if (threadIdx.x == 0 && blockIdx.x == 0) {
    int o = 0; offs[0] = 0;
    for (int e = 0; e < NE; e++) { o += (cnt[e] + 127) & ~127; offs[e + 1] = o; }
  }
}

// Per-block rank + range-reserve: 8 global atomics per block instead of 512.
__global__ __launch_bounds__(256) void assign_kernel(
    const int* __restrict__ topidx, const float* __restrict__ tgate,
    const int* __restrict__ offs, int* __restrict__ fill,
    int* __restrict__ slot_token, float* __restrict__ slot_gate) {
  __shared__ int hist[NE];
  __shared__ int base[NE];
  const int tid = threadIdx.x;
  const int t = blockIdx.x * 256 + tid;
  if (tid < NE) hist[tid] = 0;
  __syncthreads();
  int e0 = topidx[2 * t], e1 = topidx[2 * t + 1];
  float g0 = tgate[2 * t], g1 = tgate[2 * t + 1];
  int r0 = atomicAdd(&hist[e0], 1);
  int r1 = atomicAdd(&hist[e1], 1);
  __syncthreads();
  if (tid < NE) base[tid] = atomicAdd(&fill[tid], hist[tid]);
  __syncthreads();
  int s0 = offs[e0] + base[e0] + r0;
  int s1 = offs[e1] + base[e1] + r1;
  slot_token[s0] = t; slot_gate[s0] = g0;
  slot_token[s1] = t; slot_gate[s1] = g1;
}

// ---------------- GEMM1: H = relu(gather(xb) @ W1^T + b1) ----------------
// A: xb bf16 [16384][1024] gathered via slot_token ; B: w1t [E][F][D]
// C: H chunk [CHUNK_TILES*128][F]

__global__ __launch_bounds__(256) void gemm1_kernel(
    const unsigned short* __restrict__ xb, const unsigned short* __restrict__ w1t,
    const float* __restrict__ b1, const int* __restrict__ slot_token,
    const int* __restrict__ offs, unsigned short* __restrict__ H, int chunk_base) {
  __shared__ unsigned short As[128 * 32];
  __shared__ unsigned short Bs[128 * 32];
  const int tilem = chunk_base + blockIdx.y, tilen = blockIdx.x;
  const int s0 = tilem * 128;
  const int ls0 = blockIdx.y * 128;  // local H row base
  int e = -1;
#pragma unroll
  for (int i = 0; i < NE; i++)
    if (s0 >= offs[i] && s0 < offs[i + 1]) e = i;
  if (e < 0) return;  // block-uniform

  const int t = threadIdx.x;
  const int w = t >> 6, l = t & 63;
  const int wr = w >> 1, wc = w & 1;

  // staging: thread covers row srow (and srow+64), 16B chunk sp, XOR-swizzled source chunk
  const int srow = t >> 2, sp = t & 3;
  const int sc = sp ^ (srow & 3);
  int tok0 = slot_token[s0 + srow];      if (tok0 < 0) tok0 = 0;
  int tok1 = slot_token[s0 + 64 + srow]; if (tok1 < 0) tok1 = 0;
  const char* ga0 = (const char*)(xb + (size_t)tok0 * DIM) + sc * 16;
  const char* ga1 = (const char*)(xb + (size_t)tok1 * DIM) + sc * 16;
  const unsigned short* wbase = w1t + (size_t)e * FF * DIM;
  const char* gb0 = (const char*)(wbase + (size_t)(tilen * 128 + srow) * DIM) + sc * 16;
  const char* gb1 = (const char*)(wbase + (size_t)(tilen * 128 + 64 + srow) * DIM) + sc * 16;
  unsigned short* lA0 = As + w * 512;
  unsigned short* lA1 = As + 2048 + w * 512;
  unsigned short* lB0 = Bs + w * 512;
  unsigned short* lB1 = Bs + 2048 + w * 512;

  f32x4 acc[4][4];
#pragma unroll
  for (int i = 0; i < 4; i++)
#pragma unroll
    for (int j = 0; j < 4; j++) acc[i][j] = {0.f, 0.f, 0.f, 0.f};

  const int lm = l & 15, q = l >> 4;
  const int rq = (q ^ (l & 3)) << 3;  // swizzled chunk offset (shorts); row&3 == l&3 for fragment rows

  for (int kk = 0; kk < DIM / 32; kk++) {
    __syncthreads();
    gload16(ga0, lA0); gload16(ga1, lA1);
    gload16(gb0, lB0); gload16(gb1, lB1);
    ga0 += 64; ga1 += 64; gb0 += 64; gb1 += 64;
    __syncthreads();  // drains vmcnt(0) incl. global_load_lds
    bf16x8 af[4], bfr[4];
#pragma unroll
    for (int mt = 0; mt < 4; mt++) {
      int r = wr * 64 + mt * 16 + lm;
      af[mt] = *(const bf16x8*)&As[r * 32 + rq];
    }
#pragma unroll
    for (int nt = 0; nt < 4; nt++) {
      int r = wc * 64 + nt * 16 + lm;
      bfr[nt] = *(const bf16x8*)&Bs[r * 32 + rq];
    }
#pragma unroll
    for (int mt = 0; mt < 4; mt++)
#pragma unroll
      for (int nt = 0; nt < 4; nt++)
        acc[mt][nt] = __builtin_amdgcn_mfma_f32_16x16x32_bf16(af[mt], bfr[nt], acc[mt][nt], 0, 0, 0);
  }

  // epilogue: C/D layout col=lane&15 (n=f), row=(lane>>4)*4+reg (m=slot)
  const float* b1e = b1 + e * FF;
#pragma unroll
  for (int nt = 0; nt < 4; nt++) {
    int f = tilen * 128 + wc * 64 + nt * 16 + lm;
    float bias = b1e[f];
#pragma unroll
    for (int mt = 0; mt < 4; mt++) {
      int lslotb = ls0 + wr * 64 + mt * 16 + q * 4;
#pragma unroll
      for (int reg = 0; reg < 4; reg++) {
        float v = fmaxf(acc[mt][nt][reg] + bias, 0.f);
        H[(size_t)(lslotb + reg) * FF + f] = f2bf(v);
      }
    }
  }
}

// ---------------- GEMM2: d_out += gate * (H @ W2^T + b2)  (fp32 atomics) ----------------
// A: H chunk [CHUNK_TILES*128][F] ; B: w2t [E][D][F]

__global__ __launch_bounds__(256) void gemm2_kernel(
    const unsigned short* __restrict__ H, const unsigned short* __restrict__ w2t,
    const float* __restrict__ b2, const int* __restrict__ slot_token,
    const float* __restrict__ slot_gate, const int* __restrict__ offs,
    float* __restrict__ out, int chunk_base) {
  __shared__ unsigned short As[128 * 32];
  __shared__ unsigned short Bs[128 * 32];
  const int tilem = chunk_base + blockIdx.y, tilen = blockIdx.x;  // tilen: 0..7 (D tiles)
  const int s0 = tilem * 128;
  const int ls0 = blockIdx.y * 128;  // local H row base
  int e = -1;
#pragma unroll
  for (int i = 0; i < NE; i++)
    if (s0 >= offs[i] && s0 < offs[i + 1]) e = i;
  if (e < 0) return;

  const int t = threadIdx.x;
  const int w = t >> 6, l = t & 63;
  const int wr = w >> 1, wc = w & 1;
  const int srow = t >> 2, sp = t & 3;
  const int sc = sp ^ (srow & 3);
  const char* ga0 = (const char*)(H + (size_t)(ls0 + srow) * FF) + sc * 16;
  const char* ga1 = (const char*)(H + (size_t)(ls0 + 64 + srow) * FF) + sc * 16;
  const unsigned short* wbase = w2t + (size_t)e * DIM * FF;
  const char* gb0 = (const char*)(wbase + (size_t)(tilen * 128 + srow) * FF) + sc * 16;
  const char* gb1 = (const char*)(wbase + (size_t)(tilen * 128 + 64 + srow) * FF) + sc * 16;
  unsigned short* lA0 = As + w * 512;
  unsigned short* lA1 = As + 2048 + w * 512;
  unsigned short* lB0 = Bs + w * 512;
  unsigned short* lB1 = Bs + 2048 + w * 512;

  f32x4 acc[4][4];
#pragma unroll
  for (int i = 0; i < 4; i++)
#pragma unroll
    for (int j = 0; j < 4; j++) acc[i][j] = {0.f, 0.f, 0.f, 0.f};

  const int lm = l & 15, q = l >> 4;
  const int rq = (q ^ (l & 3)) << 3;

  for (int kk = 0; kk < FF / 32; kk++) {
    __syncthreads();
    gload16(ga0, lA0); gload16(ga1, lA1);
    gload16(gb0, lB0); gload16(gb1, lB1);
    ga0 += 64; ga1 += 64; gb0 += 64; gb1 += 64;
    __syncthreads();
    bf16x8 af[4], bfr[4];
#pragma unroll
    for (int mt = 0; mt < 4; mt++) {
      int r = wr * 64 + mt * 16 + lm;
      af[mt] = *(const bf16x8*)&As[r * 32 + rq];
    }
#pragma unroll
    for (int nt = 0; nt < 4; nt++) {
      int r = wc * 64 + nt * 16 + lm;
      bfr[nt] = *(const bf16x8*)&Bs[r * 32 + rq];
    }
#pragma unroll
    for (int mt = 0; mt < 4; mt++)
#pragma unroll
      for (int nt = 0; nt < 4; nt++)
        acc[mt][nt] = __builtin_amdgcn_mfma_f32_16x16x32_bf16(af[mt], bfr[nt], acc[mt][nt], 0, 0, 0);
  }

  const float* b2e = b2 + e * DIM;
  float bias[4]; int dcol[4];
#pragma unroll
  for (int nt = 0; nt < 4; nt++) {
    dcol[nt] = tilen * 128 + wc * 64 + nt * 16 + lm;
    bias[nt] = b2e[dcol[nt]];
  }
#pragma unroll
  for (int mt = 0; mt < 4; mt++) {
#pragma unroll
    for (int reg = 0; reg < 4; reg++) {
      int slot = s0 + wr * 64 + mt * 16 + q * 4 + reg;
      int tok = slot_token[slot];
      if (tok < 0) continue;  // padding slot
      float g = slot_gate[slot];
      float* orow = out + (size_t)tok * DIM;
#pragma unroll
      for (int nt = 0; nt < 4; nt++)
        atomicAdd(orow + dcol[nt], (acc[mt][nt][reg] + bias[nt]) * g);
    }
  }
}

// ---------------- launch ----------------

extern "C" void kernel_launch(void* const* d_in, const int* in_sizes, int n_in,
                              void* d_out, int out_size, void* d_ws, size_t ws_size,
                              hipStream_t stream) {
  // Reference dtypes: all inputs fp32, output fp32 (comparison done in bf16 space).
  const float* x  = (const float*)d_in[0];
  const float* Wg = (const float*)d_in[1];
  const float* W1 = (const float*)d_in[2];
  const float* b1 = (const float*)d_in[3];
  const float* W2 = (const float*)d_in[4];
  const float* b2 = (const float*)d_in[5];
  float* out = (float*)d_out;

  char* ws = (char*)d_ws;
  size_t o = 0;
  auto alloc = [&](size_t bytes) {
    void* p = ws + o; o += (bytes + 255) & ~(size_t)255; return p;
  };
  // Total footprint ~203 MB.
  unsigned short* xb  = (unsigned short*)alloc((size_t)BS_TOKENS * DIM * 2);         //  33.5 MB
  unsigned short* w1t = (unsigned short*)alloc((size_t)NE * FF * DIM * 2);           //  67.1 MB
  unsigned short* w2t = (unsigned short*)alloc((size_t)NE * DIM * FF * 2);           //  67.1 MB
  unsigned short* H   = (unsigned short*)alloc((size_t)CHUNK_TILES * 128 * FF * 2);  //  34.6 MB
  int*   slot_token   = (int*)alloc(NSLOT_CAP * 4);
  float* slot_gate    = (float*)alloc(NSLOT_CAP * 4);
  int*   topidx       = (int*)alloc(BS_TOKENS * 2 * 4);
  float* tgate        = (float*)alloc(BS_TOKENS * 2 * 4);
  float* wgt          = (float*)alloc((size_t)NE * DIM * 4);                         //  32 KB
  int*   cnt          = (int*)alloc(64);
  int*   fill         = (int*)alloc(64);
  int*   offs         = (int*)alloc(64);

  hipMemsetAsync(cnt, 0, 64, stream);
  hipMemsetAsync(fill, 0, 64, stream);
  hipMemsetAsync(slot_token, 0xFF, NSLOT_CAP * 4, stream);   // -1
  hipMemsetAsync(out, 0, (size_t)BS_TOKENS * DIM * 4, stream);  // harness poisons d_out

  cvt_x_kernel<<<BS_TOKENS * DIM / 4 / 256, 256, 0, stream>>>(x, xb);
  transpose_cvt_kernel<<<dim3(FF / 32, DIM / 32, NE), 256, 0, stream>>>(W1, w1t, DIM, FF);
  transpose_cvt_kernel<<<dim3(DIM / 32, FF / 32, NE), 256, 0, stream>>>(W2, w2t, FF, DIM);
  cvt_wg_kernel<<<DIM * NE / 256, 256, 0, stream>>>(Wg, wgt);
  router_kernel<<<BS_TOKENS / 32, 256, 0, stream>>>(x, wgt, topidx, tgate, cnt);
  mk_offs_kernel<<<1, 64, 0, stream>>>(cnt, offs);
  assign_kernel<<<BS_TOKENS / 256, 256, 0, stream>>>(topidx, tgate, offs, fill,
                                                     slot_token, slot_gate);
  for (int c = 0; c < MT_TILES; c += CHUNK_TILES) {
    gemm1_kernel<<<dim3(FF / 128, CHUNK_TILES), 256, 0, stream>>>(xb, w1t, b1, slot_token,
                                                                  offs, H, c);
    gemm2_kernel<<<dim3(DIM / 128, CHUNK_TILES), 256, 0, stream>>>(H, w2t, b2, slot_token,
                                                                   slot_gate, offs, out, c);
  }
}

// Round 2
// 1211.359 us; speedup vs baseline: 1.8294x; 1.4402x over previous
//
#include <hip/hip_runtime.h>
#include <stdint.h>

// Problem constants
#define BS_TOKENS 16384   // B*S
#define DIM 1024          // D
#define FF 4096           // F
#define NE 8              // experts
#define NSLOT_CAP 33792   // 264 * 128 (32768 slots + per-expert 128-alignment padding)
#define MT_TILES 264

typedef float f32x4 __attribute__((ext_vector_type(4)));
typedef __bf16 bf16x8 __attribute__((ext_vector_type(8)));

__device__ __forceinline__ unsigned short f2bf(float f) {
  union { float f; unsigned u; } v; v.f = f;
  unsigned u = v.u;
  unsigned r = (u + 0x7FFFu + ((u >> 16) & 1u)) >> 16;  // RNE
  return (unsigned short)r;
}

// async 16B/lane global->LDS; LDS dest is wave-uniform base + lane*16
__device__ __forceinline__ void gload16(const void* g, void* s) {
  __builtin_amdgcn_global_load_lds(
      (const __attribute__((address_space(1))) unsigned int*)g,
      (__attribute__((address_space(3))) unsigned int*)s, 16, 0, 0);
}

// ---------------- pre-passes (fp32 inputs -> bf16 staging) ----------------

__global__ __launch_bounds__(256) void cvt_x_kernel(const float* __restrict__ x,
                                                    unsigned short* __restrict__ xb) {
  int i = blockIdx.x * 256 + threadIdx.x;
  float4 v = ((const float4*)x)[i];
  ushort4 o;
  o.x = f2bf(v.x); o.y = f2bf(v.y); o.z = f2bf(v.z); o.w = f2bf(v.w);
  ((ushort4*)xb)[i] = o;
}

// src fp32 [R][C] (per expert), dst bf16 [C][R]
__global__ __launch_bounds__(256) void transpose_cvt_kernel(
    const float* __restrict__ src, unsigned short* __restrict__ dst, int R, int C) {
  __shared__ unsigned short tile[32][33];
  size_t ebase = (size_t)blockIdx.z * R * C;
  int c0 = blockIdx.x * 32, r0 = blockIdx.y * 32;
  int tx = threadIdx.x & 31, ty = threadIdx.x >> 5;  // ty 0..7
#pragma unroll
  for (int i = 0; i < 32; i += 8)
    tile[ty + i][tx] = f2bf(src[ebase + (size_t)(r0 + ty + i) * C + c0 + tx]);
  __syncthreads();
#pragma unroll
  for (int i = 0; i < 32; i += 8)
    dst[ebase + (size_t)(c0 + ty + i) * R + r0 + tx] = tile[tx][ty + i];
}

// Wg fp32 [D][E] -> wgt fp32 [E][D] (tiny: 8192 elems)
__global__ __launch_bounds__(256) void cvt_wg_kernel(const float* __restrict__ Wg,
                                                     float* __restrict__ wgt) {
  int i = blockIdx.x * 256 + threadIdx.x;  // i over D*E
  int d = i >> 3, e = i & 7;
  wgt[e * DIM + d] = Wg[i];
}

// ---------------- router (fp32) ----------------
// 32 tokens/block (8/wave), coalesced float4 x reads, wgt [E][D] reads,
// per-block LDS histogram -> 8 global atomics per block (contention fix).

__global__ __launch_bounds__(256) void router_kernel(
    const float* __restrict__ x, const float* __restrict__ wgt,
    int* __restrict__ topidx, float* __restrict__ tgate, int* __restrict__ cnt) {
  __shared__ int scnt[NE];
  const int tid = threadIdx.x;
  if (tid < NE) scnt[tid] = 0;
  __syncthreads();
  const int wid = tid >> 6, l = tid & 63;
  const int tbase = blockIdx.x * 32 + wid * 8;
  for (int tt = 0; tt < 8; tt++) {
    int token = tbase + tt;
    const float4* xr4 = (const float4*)(x + (size_t)token * DIM);
    float acc[NE];
#pragma unroll
    for (int e = 0; e < NE; e++) acc[e] = 0.f;
#pragma unroll
    for (int k = 0; k < DIM / 256; k++) {  // 4 iters, 16B/lane
      float4 xv = xr4[l + 64 * k];
      int d = (l + 64 * k) * 4;
#pragma unroll
      for (int e = 0; e < NE; e++) {
        float4 wv = *(const float4*)(wgt + e * DIM + d);
        acc[e] += xv.x * wv.x + xv.y * wv.y + xv.z * wv.z + xv.w * wv.w;
      }
    }
#pragma unroll
    for (int e = 0; e < NE; e++) {
#pragma unroll
      for (int off = 32; off > 0; off >>= 1) acc[e] += __shfl_xor(acc[e], off);
    }
    if (l == 0) {
      float m = acc[0];
#pragma unroll
      for (int e = 1; e < NE; e++) m = fmaxf(m, acc[e]);
      float p[NE];
#pragma unroll
      for (int e = 0; e < NE; e++) p[e] = __expf(acc[e] - m);
      int i1 = 0;
#pragma unroll
      for (int e = 1; e < NE; e++) if (p[e] > p[i1]) i1 = e;   // strict > : first index on tie
      int i2 = -1;
#pragma unroll
      for (int e = 0; e < NE; e++) {
        if (e == i1) continue;
        if (i2 < 0 || p[e] > p[i2]) i2 = e;
      }
      float s = p[i1] + p[i2];
      topidx[2 * token] = i1; topidx[2 * token + 1] = i2;
      tgate[2 * token] = p[i1] / s; tgate[2 * token + 1] = p[i2] / s;
      atomicAdd(&scnt[i1], 1); atomicAdd(&scnt[i2], 1);
    }
  }
  __syncthreads();
  if (tid < NE) atomicAdd(&cnt[tid], scnt[tid]);
}

__global__ void mk_offs_kernel(const int* __restrict__ cnt, int* __restrict__ offs) {
  if (threadIdx.x == 0 && blockIdx.x == 0) {
    int o = 0; offs[0] = 0;
    for (int e = 0; e < NE; e++) { o += (cnt[e] + 127) & ~127; offs[e + 1] = o; }
  }
}

// Per-block rank + range-reserve: 8 global atomics per block instead of 512.
__global__ __launch_bounds__(256) void assign_kernel(
    const int* __restrict__ topidx, const float* __restrict__ tgate,
    const int* __restrict__ offs, int* __restrict__ fill,
    int* __restrict__ slot_token, float* __restrict__ slot_gate) {
  __shared__ int hist[NE];
  __shared__ int base[NE];
  const int tid = threadIdx.x;
  const int t = blockIdx.x * 256 + tid;
  if (tid < NE) hist[tid] = 0;
  __syncthreads();
  int e0 = topidx[2 * t], e1 = topidx[2 * t + 1];
  float g0 = tgate[2 * t], g1 = tgate[2 * t + 1];
  int r0 = atomicAdd(&hist[e0], 1);
  int r1 = atomicAdd(&hist[e1], 1);
  __syncthreads();
  if (tid < NE) base[tid] = atomicAdd(&fill[tid], hist[tid]);
  __syncthreads();
  int s0 = offs[e0] + base[e0] + r0;
  int s1 = offs[e1] + base[e1] + r1;
  slot_token[s0] = t; slot_gate[s0] = g0;
  slot_token[s1] = t; slot_gate[s1] = g1;
}

// ---------------- GEMM1: H = relu(gather(xb) @ W1^T + b1) ----------------
// A: xb bf16 [16384][1024] gathered via slot_token ; B: w1t [E][F][D]
// C: H chunk [ct*128][F]

__global__ __launch_bounds__(256) void gemm1_kernel(
    const unsigned short* __restrict__ xb, const unsigned short* __restrict__ w1t,
    const float* __restrict__ b1, const int* __restrict__ slot_token,
    const int* __restrict__ offs, unsigned short* __restrict__ H, int chunk_base) {
  __shared__ unsigned short As[128 * 32];
  __shared__ unsigned short Bs[128 * 32];
  const int tilem = chunk_base + blockIdx.y, tilen = blockIdx.x;
  const int s0 = tilem * 128;
  const int ls0 = blockIdx.y * 128;  // local H row base
  int e = -1;
#pragma unroll
  for (int i = 0; i < NE; i++)
    if (s0 >= offs[i] && s0 < offs[i + 1]) e = i;
  if (e < 0) return;  // block-uniform

  const int t = threadIdx.x;
  const int w = t >> 6, l = t & 63;
  const int wr = w >> 1, wc = w & 1;

  // staging: thread covers row srow (and srow+64), 16B chunk sp, XOR-swizzled source chunk
  const int srow = t >> 2, sp = t & 3;
  const int sc = sp ^ (srow & 3);
  int tok0 = slot_token[s0 + srow];      if (tok0 < 0) tok0 = 0;
  int tok1 = slot_token[s0 + 64 + srow]; if (tok1 < 0) tok1 = 0;
  const char* ga0 = (const char*)(xb + (size_t)tok0 * DIM) + sc * 16;
  const char* ga1 = (const char*)(xb + (size_t)tok1 * DIM) + sc * 16;
  const unsigned short* wbase = w1t + (size_t)e * FF * DIM;
  const char* gb0 = (const char*)(wbase + (size_t)(tilen * 128 + srow) * DIM) + sc * 16;
  const char* gb1 = (const char*)(wbase + (size_t)(tilen * 128 + 64 + srow) * DIM) + sc * 16;
  unsigned short* lA0 = As + w * 512;
  unsigned short* lA1 = As + 2048 + w * 512;
  unsigned short* lB0 = Bs + w * 512;
  unsigned short* lB1 = Bs + 2048 + w * 512;

  f32x4 acc[4][4];
#pragma unroll
  for (int i = 0; i < 4; i++)
#pragma unroll
    for (int j = 0; j < 4; j++) acc[i][j] = {0.f, 0.f, 0.f, 0.f};

  const int lm = l & 15, q = l >> 4;
  const int rq = (q ^ (l & 3)) << 3;  // swizzled chunk offset (shorts); row&3 == l&3 for fragment rows

  for (int kk = 0; kk < DIM / 32; kk++) {
    __syncthreads();
    gload16(ga0, lA0); gload16(ga1, lA1);
    gload16(gb0, lB0); gload16(gb1, lB1);
    ga0 += 64; ga1 += 64; gb0 += 64; gb1 += 64;
    __syncthreads();  // drains vmcnt(0) incl. global_load_lds
    bf16x8 af[4], bfr[4];
#pragma unroll
    for (int mt = 0; mt < 4; mt++) {
      int r = wr * 64 + mt * 16 + lm;
      af[mt] = *(const bf16x8*)&As[r * 32 + rq];
    }
#pragma unroll
    for (int nt = 0; nt < 4; nt++) {
      int r = wc * 64 + nt * 16 + lm;
      bfr[nt] = *(const bf16x8*)&Bs[r * 32 + rq];
    }
#pragma unroll
    for (int mt = 0; mt < 4; mt++)
#pragma unroll
      for (int nt = 0; nt < 4; nt++)
        acc[mt][nt] = __builtin_amdgcn_mfma_f32_16x16x32_bf16(af[mt], bfr[nt], acc[mt][nt], 0, 0, 0);
  }

  // epilogue: C/D layout col=lane&15 (n=f), row=(lane>>4)*4+reg (m=slot)
  const float* b1e = b1 + e * FF;
#pragma unroll
  for (int nt = 0; nt < 4; nt++) {
    int f = tilen * 128 + wc * 64 + nt * 16 + lm;
    float bias = b1e[f];
#pragma unroll
    for (int mt = 0; mt < 4; mt++) {
      int lslotb = ls0 + wr * 64 + mt * 16 + q * 4;
#pragma unroll
      for (int reg = 0; reg < 4; reg++) {
        float v = fmaxf(acc[mt][nt][reg] + bias, 0.f);
        H[(size_t)(lslotb + reg) * FF + f] = f2bf(v);
      }
    }
  }
}

// ---------------- GEMM2: d_out += gate * (H @ W2^T + b2)  (fp32 atomics) ----------------
// A: H chunk [ct*128][F] ; B: w2t [E][D][F]

__global__ __launch_bounds__(256) void gemm2_kernel(
    const unsigned short* __restrict__ H, const unsigned short* __restrict__ w2t,
    const float* __restrict__ b2, const int* __restrict__ slot_token,
    const float* __restrict__ slot_gate, const int* __restrict__ offs,
    float* __restrict__ out, int chunk_base) {
  __shared__ unsigned short As[128 * 32];
  __shared__ unsigned short Bs[128 * 32];
  const int tilem = chunk_base + blockIdx.y, tilen = blockIdx.x;  // tilen: 0..7 (D tiles)
  const int s0 = tilem * 128;
  const int ls0 = blockIdx.y * 128;  // local H row base
  int e = -1;
#pragma unroll
  for (int i = 0; i < NE; i++)
    if (s0 >= offs[i] && s0 < offs[i + 1]) e = i;
  if (e < 0) return;

  const int t = threadIdx.x;
  const int w = t >> 6, l = t & 63;
  const int wr = w >> 1, wc = w & 1;
  const int srow = t >> 2, sp = t & 3;
  const int sc = sp ^ (srow & 3);
  const char* ga0 = (const char*)(H + (size_t)(ls0 + srow) * FF) + sc * 16;
  const char* ga1 = (const char*)(H + (size_t)(ls0 + 64 + srow) * FF) + sc * 16;
  const unsigned short* wbase = w2t + (size_t)e * DIM * FF;
  const char* gb0 = (const char*)(wbase + (size_t)(tilen * 128 + srow) * FF) + sc * 16;
  const char* gb1 = (const char*)(wbase + (size_t)(tilen * 128 + 64 + srow) * FF) + sc * 16;
  unsigned short* lA0 = As + w * 512;
  unsigned short* lA1 = As + 2048 + w * 512;
  unsigned short* lB0 = Bs + w * 512;
  unsigned short* lB1 = Bs + 2048 + w * 512;

  f32x4 acc[4][4];
#pragma unroll
  for (int i = 0; i < 4; i++)
#pragma unroll
    for (int j = 0; j < 4; j++) acc[i][j] = {0.f, 0.f, 0.f, 0.f};

  const int lm = l & 15, q = l >> 4;
  const int rq = (q ^ (l & 3)) << 3;

  for (int kk = 0; kk < FF / 32; kk++) {
    __syncthreads();
    gload16(ga0, lA0); gload16(ga1, lA1);
    gload16(gb0, lB0); gload16(gb1, lB1);
    ga0 += 64; ga1 += 64; gb0 += 64; gb1 += 64;
    __syncthreads();
    bf16x8 af[4], bfr[4];
#pragma unroll
    for (int mt = 0; mt < 4; mt++) {
      int r = wr * 64 + mt * 16 + lm;
      af[mt] = *(const bf16x8*)&As[r * 32 + rq];
    }
#pragma unroll
    for (int nt = 0; nt < 4; nt++) {
      int r = wc * 64 + nt * 16 + lm;
      bfr[nt] = *(const bf16x8*)&Bs[r * 32 + rq];
    }
#pragma unroll
    for (int mt = 0; mt < 4; mt++)
#pragma unroll
      for (int nt = 0; nt < 4; nt++)
        acc[mt][nt] = __builtin_amdgcn_mfma_f32_16x16x32_bf16(af[mt], bfr[nt], acc[mt][nt], 0, 0, 0);
  }

  const float* b2e = b2 + e * DIM;
  float bias[4]; int dcol[4];
#pragma unroll
  for (int nt = 0; nt < 4; nt++) {
    dcol[nt] = tilen * 128 + wc * 64 + nt * 16 + lm;
    bias[nt] = b2e[dcol[nt]];
  }
#pragma unroll
  for (int mt = 0; mt < 4; mt++) {
#pragma unroll
    for (int reg = 0; reg < 4; reg++) {
      int slot = s0 + wr * 64 + mt * 16 + q * 4 + reg;
      int tok = slot_token[slot];
      if (tok < 0) continue;  // padding slot
      float g = slot_gate[slot];
      float* orow = out + (size_t)tok * DIM;
#pragma unroll
      for (int nt = 0; nt < 4; nt++)
        atomicAdd(orow + dcol[nt], (acc[mt][nt][reg] + bias[nt]) * g);
    }
  }
}

// ---------------- launch ----------------

extern "C" void kernel_launch(void* const* d_in, const int* in_sizes, int n_in,
                              void* d_out, int out_size, void* d_ws, size_t ws_size,
                              hipStream_t stream) {
  // Reference dtypes: all inputs fp32, output fp32 (comparison done in bf16 space).
  const float* x  = (const float*)d_in[0];
  const float* Wg = (const float*)d_in[1];
  const float* W1 = (const float*)d_in[2];
  const float* b1 = (const float*)d_in[3];
  const float* W2 = (const float*)d_in[4];
  const float* b2 = (const float*)d_in[5];
  float* out = (float*)d_out;

  char* ws = (char*)d_ws;
  size_t o = 0;
  auto rup = [](size_t b) { return (b + 255) & ~(size_t)255; };
  auto alloc = [&](size_t bytes) {
    void* p = ws + o; o += rup(bytes); return p;
  };

  // Pick the largest H-chunk (in 128-slot tiles) that fits the workspace.
  // ct=264 -> single chunk (grid y=264 -> 2112/8448 blocks, full occupancy);
  // smaller values fall back gracefully (264 = 8*33, all candidates divide it).
  size_t fixed = rup((size_t)BS_TOKENS * DIM * 2)      // xb
               + rup((size_t)NE * FF * DIM * 2) * 2    // w1t, w2t
               + rup((size_t)NSLOT_CAP * 4) * 2        // slot_token, slot_gate
               + rup((size_t)BS_TOKENS * 2 * 4) * 2    // topidx, tgate
               + rup((size_t)NE * DIM * 4)             // wgt
               + rup(64) * 3;                          // cnt, fill, offs
  int ct = 33;
  const int cands[3] = {264, 132, 66};
  for (int i = 0; i < 3; i++) {
    size_t need = fixed + rup((size_t)cands[i] * 128 * FF * 2);
    if (ws_size >= need) { ct = cands[i]; break; }
  }

  unsigned short* xb  = (unsigned short*)alloc((size_t)BS_TOKENS * DIM * 2);       //  33.5 MB
  unsigned short* w1t = (unsigned short*)alloc((size_t)NE * FF * DIM * 2);         //  67.1 MB
  unsigned short* w2t = (unsigned short*)alloc((size_t)NE * DIM * FF * 2);         //  67.1 MB
  unsigned short* H   = (unsigned short*)alloc((size_t)ct * 128 * FF * 2);         //  up to 277 MB
  int*   slot_token   = (int*)alloc(NSLOT_CAP * 4);
  float* slot_gate    = (float*)alloc(NSLOT_CAP * 4);
  int*   topidx       = (int*)alloc(BS_TOKENS * 2 * 4);
  float* tgate        = (float*)alloc(BS_TOKENS * 2 * 4);
  float* wgt          = (float*)alloc((size_t)NE * DIM * 4);                       //  32 KB
  int*   cnt          = (int*)alloc(64);
  int*   fill         = (int*)alloc(64);
  int*   offs         = (int*)alloc(64);

  hipMemsetAsync(cnt, 0, 64, stream);
  hipMemsetAsync(fill, 0, 64, stream);
  hipMemsetAsync(slot_token, 0xFF, NSLOT_CAP * 4, stream);   // -1
  hipMemsetAsync(out, 0, (size_t)BS_TOKENS * DIM * 4, stream);  // harness poisons d_out

  cvt_x_kernel<<<BS_TOKENS * DIM / 4 / 256, 256, 0, stream>>>(x, xb);
  transpose_cvt_kernel<<<dim3(FF / 32, DIM / 32, NE), 256, 0, stream>>>(W1, w1t, DIM, FF);
  transpose_cvt_kernel<<<dim3(DIM / 32, FF / 32, NE), 256, 0, stream>>>(W2, w2t, FF, DIM);
  cvt_wg_kernel<<<DIM * NE / 256, 256, 0, stream>>>(Wg, wgt);
  router_kernel<<<BS_TOKENS / 32, 256, 0, stream>>>(x, wgt, topidx, tgate, cnt);
  mk_offs_kernel<<<1, 64, 0, stream>>>(cnt, offs);
  assign_kernel<<<BS_TOKENS / 256, 256, 0, stream>>>(topidx, tgate, offs, fill,
                                                     slot_token, slot_gate);
  for (int c = 0; c < MT_TILES; c += ct) {
    gemm1_kernel<<<dim3(FF / 128, ct), 256, 0, stream>>>(xb, w1t, b1, slot_token,
                                                         offs, H, c);
    gemm2_kernel<<<dim3(DIM / 128, ct), 256, 0, stream>>>(H, w2t, b2, slot_token,
                                                          slot_gate, offs, out, c);
  }
}